// Round 1
// baseline (142.007 us; speedup 1.0000x reference)
//
#include <hip/hip_runtime.h>

#define DEV static __device__ __forceinline__

DEV float shflx(float v, int mask) { return __shfl_xor(v, mask, 64); }

// Qubit q <-> bit P = 9-q of state index s = lane*16 + r.
// Bits 9..4 = lane bits (lane bit P-4), bits 3..0 = register bits.

template <int P>
DEV void apply_ry(float (&re)[16], float (&im)[16], float c, float s, int lane) {
    if constexpr (P >= 4) {
        constexpr int mask = 1 << (P - 4);
        const float sg = (lane & mask) ? s : -s;  // bit0: c*own - s*partner ; bit1: c*own + s*partner
#pragma unroll
        for (int r = 0; r < 16; ++r) {
            float pr = shflx(re[r], mask);
            float pi = shflx(im[r], mask);
            re[r] = fmaf(c, re[r], sg * pr);
            im[r] = fmaf(c, im[r], sg * pi);
        }
    } else {
        constexpr int tb = 1 << P;
#pragma unroll
        for (int r = 0; r < 16; ++r) {
            if (!(r & tb)) {
                const int r2 = r | tb;
                float a0r = re[r], a1r = re[r2];
                float a0i = im[r], a1i = im[r2];
                re[r]  = fmaf(c, a0r, -s * a1r);
                re[r2] = fmaf(s, a0r,  c * a1r);
                im[r]  = fmaf(c, a0i, -s * a1i);
                im[r2] = fmaf(s, a0i,  c * a1i);
            }
        }
    }
}

template <int P>
DEV void apply_rz(float (&re)[16], float (&im)[16], float c, float s, int lane) {
    // bit=0: multiply by (c, -s); bit=1: by (c, +s).  sg = +-s
    if constexpr (P >= 4) {
        constexpr int mask = 1 << (P - 4);
        const float sg = (lane & mask) ? s : -s;
#pragma unroll
        for (int r = 0; r < 16; ++r) {
            float nr = fmaf(c, re[r], -sg * im[r]);
            float ni = fmaf(sg, re[r], c * im[r]);
            re[r] = nr; im[r] = ni;
        }
    } else {
        constexpr int tb = 1 << P;
#pragma unroll
        for (int r = 0; r < 16; ++r) {
            const float sg = (r & tb) ? s : -s;
            float nr = fmaf(c, re[r], -sg * im[r]);
            float ni = fmaf(sg, re[r], c * im[r]);
            re[r] = nr; im[r] = ni;
        }
    }
}

template <int PC, int PT>
DEV void apply_cnot(float (&re)[16], float (&im)[16], int lane) {
    if constexpr (PT >= 4) {
        constexpr int tmask = 1 << (PT - 4);
        if constexpr (PC >= 4) {
            const bool ctrl = (lane & (1 << (PC - 4))) != 0;
#pragma unroll
            for (int r = 0; r < 16; ++r) {
                float pr = shflx(re[r], tmask);
                float pi = shflx(im[r], tmask);
                re[r] = ctrl ? pr : re[r];
                im[r] = ctrl ? pi : im[r];
            }
        } else {
            // control is a register bit: only registers with that bit set exchange
#pragma unroll
            for (int r = 0; r < 16; ++r) {
                if (r & (1 << PC)) {
                    re[r] = shflx(re[r], tmask);
                    im[r] = shflx(im[r], tmask);
                }
            }
        }
    } else {
        constexpr int tb = 1 << PT;
        if constexpr (PC >= 4) {
            const bool ctrl = (lane & (1 << (PC - 4))) != 0;
#pragma unroll
            for (int r = 0; r < 16; ++r) {
                if (!(r & tb)) {
                    const int r2 = r | tb;
                    float t0 = re[r], t1 = re[r2];
                    re[r]  = ctrl ? t1 : t0;
                    re[r2] = ctrl ? t0 : t1;
                    float u0 = im[r], u1 = im[r2];
                    im[r]  = ctrl ? u1 : u0;
                    im[r2] = ctrl ? u0 : u1;
                }
            }
        } else {
            // pure compile-time register permutation
#pragma unroll
            for (int r = 0; r < 16; ++r) {
                if ((r & (1 << PC)) && !(r & tb)) {
                    const int r2 = r | tb;
                    float t = re[r]; re[r] = re[r2]; re[r2] = t;
                    t = im[r]; im[r] = im[r2]; im[r2] = t;
                }
            }
        }
    }
}

// Precompute cos/sin of weight angles (batch-independent) into workspace.
__global__ void dqc_trig_kernel(const float* __restrict__ w_ry,
                                const float* __restrict__ w_rz,
                                float2* __restrict__ trig) {
    int t = threadIdx.x;  // 0..79
    if (t < 80) {
        float ang = (t < 40 ? w_ry[t] : w_rz[t - 40]) * 0.5f;
        float s, c;
        sincosf(ang, &s, &c);
        trig[t] = make_float2(c, s);
    }
}

__global__ __launch_bounds__(256, 4) void dqc_main_kernel(
    const float* __restrict__ x, const float* __restrict__ pre_w,
    const float* __restrict__ pre_b, const float* __restrict__ post_w,
    const float* __restrict__ post_b, const float2* __restrict__ trig,
    float* __restrict__ out, int B) {
    const int lane = threadIdx.x & 63;
    const int wid = threadIdx.x >> 6;
    const int b = blockIdx.x * 4 + wid;
    if (b >= B) return;

    // ---- q_in[b, i] = x[b] . pre_w[i] + pre_b[i]  (i = 0..9) ----
    float th[10];
#pragma unroll
    for (int i = 0; i < 10; ++i) th[i] = 0.f;
    const float* xb = x + (size_t)b * 512;
#pragma unroll
    for (int k = 0; k < 8; ++k) {
        const int idx = lane + 64 * k;
        float xv = xb[idx];
#pragma unroll
        for (int i = 0; i < 10; ++i) th[i] = fmaf(xv, pre_w[i * 512 + idx], th[i]);
    }
#pragma unroll
    for (int i = 0; i < 10; ++i) {
#pragma unroll
        for (int off = 32; off; off >>= 1) th[i] += shflx(th[i], off);
        th[i] += pre_b[i];
    }

    // ---- state init |0...0> ----
    float re[16], im[16];
#pragma unroll
    for (int r = 0; r < 16; ++r) { re[r] = 0.f; im[r] = 0.f; }
    re[0] = (lane == 0) ? 1.f : 0.f;

    // ---- initial RY layer from data ----
#define INIT_Q(Q)                                        \
    {                                                    \
        float ss, cc;                                    \
        sincosf(th[Q] * 0.5f, &ss, &cc);                 \
        apply_ry<9 - (Q)>(re, im, cc, ss, lane);         \
    }
    INIT_Q(0) INIT_Q(1) INIT_Q(2) INIT_Q(3) INIT_Q(4)
    INIT_Q(5) INIT_Q(6) INIT_Q(7) INIT_Q(8) INIT_Q(9)
#undef INIT_Q

    // ---- variational layers ----
    for (int l = 0; l < 4; ++l) {
        const int base = l * 10;
#define LAYER_Q(Q)                                                 \
        {                                                          \
            float2 t1 = trig[base + (Q)];                          \
            apply_ry<9 - (Q)>(re, im, t1.x, t1.y, lane);           \
            float2 t2 = trig[40 + base + (Q)];                     \
            apply_rz<9 - (Q)>(re, im, t2.x, t2.y, lane);           \
        }
        LAYER_Q(0) LAYER_Q(1) LAYER_Q(2) LAYER_Q(3) LAYER_Q(4)
        LAYER_Q(5) LAYER_Q(6) LAYER_Q(7) LAYER_Q(8) LAYER_Q(9)
#undef LAYER_Q
        // CNOT ring: control qubit i (bit 9-i) -> target qubit (i+1)%10
        apply_cnot<9, 8>(re, im, lane);
        apply_cnot<8, 7>(re, im, lane);
        apply_cnot<7, 6>(re, im, lane);
        apply_cnot<6, 5>(re, im, lane);
        apply_cnot<5, 4>(re, im, lane);
        apply_cnot<4, 3>(re, im, lane);
        apply_cnot<3, 2>(re, im, lane);
        apply_cnot<2, 1>(re, im, lane);
        apply_cnot<1, 0>(re, im, lane);
        apply_cnot<0, 9>(re, im, lane);
    }

    // ---- out[b] = sum_s |psi_s|^2 * sum_j post_w[j]*(1-2*bit_j(s)) + post_b ----
    float laneC = 0.f;
#pragma unroll
    for (int j = 0; j < 6; ++j) {  // qubits 0..5 live in lane bits 5-j
        int bit = (lane >> (5 - j)) & 1;
        laneC += post_w[j] * (1.f - 2.f * (float)bit);
    }
    float acc = 0.f;
#pragma unroll
    for (int r = 0; r < 16; ++r) {
        float regC = 0.f;
#pragma unroll
        for (int j = 6; j < 10; ++j) {  // qubits 6..9 live in reg bits 9-j
            int bit = (r >> (9 - j)) & 1;
            regC += post_w[j] * (1.f - 2.f * (float)bit);
        }
        float p = fmaf(re[r], re[r], im[r] * im[r]);
        acc = fmaf(p, laneC + regC, acc);
    }
#pragma unroll
    for (int off = 32; off; off >>= 1) acc += shflx(acc, off);
    if (lane == 0) out[b] = acc + post_b[0];
}

extern "C" void kernel_launch(void* const* d_in, const int* in_sizes, int n_in,
                              void* d_out, int out_size, void* d_ws, size_t ws_size,
                              hipStream_t stream) {
    const float* x      = (const float*)d_in[0];
    const float* pre_w  = (const float*)d_in[1];
    const float* pre_b  = (const float*)d_in[2];
    const float* post_w = (const float*)d_in[3];
    const float* post_b = (const float*)d_in[4];
    const float* w_ry   = (const float*)d_in[5];
    const float* w_rz   = (const float*)d_in[6];
    float* out = (float*)d_out;
    float2* trig = (float2*)d_ws;

    const int B = in_sizes[0] / 512;  // 4096

    dqc_trig_kernel<<<1, 128, 0, stream>>>(w_ry, w_rz, trig);
    dqc_main_kernel<<<(B + 3) / 4, 256, 0, stream>>>(x, pre_w, pre_b, post_w,
                                                     post_b, trig, out, B);
}

// Round 2
// 124.459 us; speedup vs baseline: 1.1410x; 1.1410x over previous
//
#include <hip/hip_runtime.h>

#define DEV static __device__ __forceinline__

// ---- lane exchange: DPP (VALU pipe) for masks 1,2,8; ds_swizzle/permute (LDS pipe) otherwise ----
template <int CTRL>
DEV float dpp_xor(float v) {
    int i = __float_as_int(v);
    i = __builtin_amdgcn_update_dpp(i, i, CTRL, 0xF, 0xF, false);
    return __int_as_float(i);
}

template <int MASK>
DEV float lanexor(float v) {
    if constexpr (MASK == 1)      return dpp_xor<0xB1>(v);   // quad_perm [1,0,3,2]
    else if constexpr (MASK == 2) return dpp_xor<0x4E>(v);   // quad_perm [2,3,0,1]
    else if constexpr (MASK == 8) return dpp_xor<0x128>(v);  // row_ror:8 == xor 8 within 16
    else return __shfl_xor(v, MASK, 64);
}

DEV float wave_sum(float v) {
    v += lanexor<1>(v);
    v += lanexor<2>(v);
    v += lanexor<4>(v);
    v += lanexor<8>(v);
    v += lanexor<16>(v);
    v += lanexor<32>(v);
    return v;
}

// Qubit q <-> bit P = 9-q of state index s = lane*16 + r.
// Bits 9..4 = lane bits (lane bit P-4), bits 3..0 = register bits.

template <int P>
DEV void apply_ry(float (&re)[16], float (&im)[16], float c, float s, int lane) {
    if constexpr (P >= 4) {
        constexpr int mask = 1 << (P - 4);
        const float sg = (lane & mask) ? s : -s;
#pragma unroll
        for (int r = 0; r < 16; ++r) {
            float pr = lanexor<mask>(re[r]);
            float pi = lanexor<mask>(im[r]);
            re[r] = fmaf(c, re[r], sg * pr);
            im[r] = fmaf(c, im[r], sg * pi);
        }
    } else {
        constexpr int tb = 1 << P;
#pragma unroll
        for (int r = 0; r < 16; ++r) {
            if (!(r & tb)) {
                const int r2 = r | tb;
                float a0r = re[r], a1r = re[r2];
                float a0i = im[r], a1i = im[r2];
                re[r]  = fmaf(c, a0r, -s * a1r);
                re[r2] = fmaf(s, a0r,  c * a1r);
                im[r]  = fmaf(c, a0i, -s * a1i);
                im[r2] = fmaf(s, a0i,  c * a1i);
            }
        }
    }
}

template <int P>
DEV void apply_rz(float (&re)[16], float (&im)[16], float c, float s, int lane) {
    if constexpr (P >= 4) {
        constexpr int mask = 1 << (P - 4);
        const float sg = (lane & mask) ? s : -s;
#pragma unroll
        for (int r = 0; r < 16; ++r) {
            float nr = fmaf(c, re[r], -sg * im[r]);
            float ni = fmaf(sg, re[r], c * im[r]);
            re[r] = nr; im[r] = ni;
        }
    } else {
        constexpr int tb = 1 << P;
#pragma unroll
        for (int r = 0; r < 16; ++r) {
            const float sg = (r & tb) ? s : -s;
            float nr = fmaf(c, re[r], -sg * im[r]);
            float ni = fmaf(sg, re[r], c * im[r]);
            re[r] = nr; im[r] = ni;
        }
    }
}

template <int PC, int PT>
DEV void apply_cnot(float (&re)[16], float (&im)[16], int lane) {
    if constexpr (PT >= 4) {
        constexpr int tmask = 1 << (PT - 4);
        if constexpr (PC >= 4) {
            const bool ctrl = (lane & (1 << (PC - 4))) != 0;
#pragma unroll
            for (int r = 0; r < 16; ++r) {
                float pr = lanexor<tmask>(re[r]);
                float pi = lanexor<tmask>(im[r]);
                re[r] = ctrl ? pr : re[r];
                im[r] = ctrl ? pi : im[r];
            }
        } else {
#pragma unroll
            for (int r = 0; r < 16; ++r) {
                if (r & (1 << PC)) {
                    re[r] = lanexor<tmask>(re[r]);
                    im[r] = lanexor<tmask>(im[r]);
                }
            }
        }
    } else {
        constexpr int tb = 1 << PT;
        if constexpr (PC >= 4) {
            const bool ctrl = (lane & (1 << (PC - 4))) != 0;
#pragma unroll
            for (int r = 0; r < 16; ++r) {
                if (!(r & tb)) {
                    const int r2 = r | tb;
                    float t0 = re[r], t1 = re[r2];
                    re[r]  = ctrl ? t1 : t0;
                    re[r2] = ctrl ? t0 : t1;
                    float u0 = im[r], u1 = im[r2];
                    im[r]  = ctrl ? u1 : u0;
                    im[r2] = ctrl ? u0 : u1;
                }
            }
        } else {
#pragma unroll
            for (int r = 0; r < 16; ++r) {
                if ((r & (1 << PC)) && !(r & tb)) {
                    const int r2 = r | tb;
                    float t = re[r]; re[r] = re[r2]; re[r2] = t;
                    t = im[r]; im[r] = im[r2]; im[r2] = t;
                }
            }
        }
    }
}

// Precompute cos/sin of weight angles (batch-independent) into workspace.
__global__ void dqc_trig_kernel(const float* __restrict__ w_ry,
                                const float* __restrict__ w_rz,
                                float2* __restrict__ trig) {
    int t = threadIdx.x;  // 0..79
    if (t < 80) {
        float ang = (t < 40 ? w_ry[t] : w_rz[t - 40]) * 0.5f;
        float s, c;
        sincosf(ang, &s, &c);
        trig[t] = make_float2(c, s);
    }
}

__global__ __launch_bounds__(256, 4) void dqc_main_kernel(
    const float* __restrict__ x, const float* __restrict__ pre_w,
    const float* __restrict__ pre_b, const float* __restrict__ post_w,
    const float* __restrict__ post_b, const float2* __restrict__ trig,
    float* __restrict__ out, int B) {
    const int lane = threadIdx.x & 63;
    const int wid = threadIdx.x >> 6;
    const int b = blockIdx.x * 4 + wid;
    if (b >= B) return;

    // ---- q_in[b, i] = x[b] . pre_w[i] + pre_b[i]  (i = 0..9) ----
    float th[10];
#pragma unroll
    for (int i = 0; i < 10; ++i) th[i] = 0.f;
    const float* xb = x + (size_t)b * 512;
#pragma unroll
    for (int k = 0; k < 8; ++k) {
        const int idx = lane + 64 * k;
        float xv = xb[idx];
#pragma unroll
        for (int i = 0; i < 10; ++i) th[i] = fmaf(xv, pre_w[i * 512 + idx], th[i]);
    }
#pragma unroll
    for (int i = 0; i < 10; ++i) th[i] = wave_sum(th[i]) + pre_b[i];

    // ---- product-state construction: state after 10 initial RYs on |0..0> is
    //      amp(s) = prod_i (bit_i(s) ? sin(th_i/2) : cos(th_i/2)), purely real ----
    float cc[10], ss[10];
#pragma unroll
    for (int i = 0; i < 10; ++i) sincosf(th[i] * 0.5f, &ss[i], &cc[i]);

    float laneP = 1.f;
#pragma unroll
    for (int i = 0; i < 6; ++i)  // qubit i <-> lane bit 5-i
        laneP *= ((lane >> (5 - i)) & 1) ? ss[i] : cc[i];

    float hi[4], lo[4];
#pragma unroll
    for (int j = 0; j < 4; ++j) {
        float f6 = (j >> 1) ? ss[6] : cc[6];  // qubit6 <-> reg bit 3
        float f7 = (j & 1) ? ss[7] : cc[7];   // qubit7 <-> reg bit 2
        hi[j] = laneP * f6 * f7;
        float f8 = (j >> 1) ? ss[8] : cc[8];  // qubit8 <-> reg bit 1
        float f9 = (j & 1) ? ss[9] : cc[9];   // qubit9 <-> reg bit 0
        lo[j] = f8 * f9;
    }
    float re[16], im[16];
#pragma unroll
    for (int r = 0; r < 16; ++r) { re[r] = hi[r >> 2] * lo[r & 3]; im[r] = 0.f; }

    // ---- variational layers ----
    for (int l = 0; l < 4; ++l) {
        const int base = l * 10;
#define LAYER_Q(Q)                                                 \
        {                                                          \
            float2 t1 = trig[base + (Q)];                          \
            apply_ry<9 - (Q)>(re, im, t1.x, t1.y, lane);           \
            float2 t2 = trig[40 + base + (Q)];                     \
            apply_rz<9 - (Q)>(re, im, t2.x, t2.y, lane);           \
        }
        LAYER_Q(0) LAYER_Q(1) LAYER_Q(2) LAYER_Q(3) LAYER_Q(4)
        LAYER_Q(5) LAYER_Q(6) LAYER_Q(7) LAYER_Q(8) LAYER_Q(9)
#undef LAYER_Q
        // CNOT ring: control qubit i (bit 9-i) -> target qubit (i+1)%10
        apply_cnot<9, 8>(re, im, lane);
        apply_cnot<8, 7>(re, im, lane);
        apply_cnot<7, 6>(re, im, lane);
        apply_cnot<6, 5>(re, im, lane);
        apply_cnot<5, 4>(re, im, lane);
        apply_cnot<4, 3>(re, im, lane);
        apply_cnot<3, 2>(re, im, lane);
        apply_cnot<2, 1>(re, im, lane);
        apply_cnot<1, 0>(re, im, lane);
        apply_cnot<0, 9>(re, im, lane);
    }

    // ---- out[b] = sum_s |psi_s|^2 * sum_j post_w[j]*(1-2*bit_j(s)) + post_b ----
    float laneC = 0.f;
#pragma unroll
    for (int j = 0; j < 6; ++j) {
        int bit = (lane >> (5 - j)) & 1;
        laneC += post_w[j] * (1.f - 2.f * (float)bit);
    }
    float acc = 0.f;
#pragma unroll
    for (int r = 0; r < 16; ++r) {
        float regC = 0.f;
#pragma unroll
        for (int j = 6; j < 10; ++j) {
            int bit = (r >> (9 - j)) & 1;
            regC += post_w[j] * (1.f - 2.f * (float)bit);
        }
        float p = fmaf(re[r], re[r], im[r] * im[r]);
        acc = fmaf(p, laneC + regC, acc);
    }
    acc = wave_sum(acc);
    if (lane == 0) out[b] = acc + post_b[0];
}

extern "C" void kernel_launch(void* const* d_in, const int* in_sizes, int n_in,
                              void* d_out, int out_size, void* d_ws, size_t ws_size,
                              hipStream_t stream) {
    const float* x      = (const float*)d_in[0];
    const float* pre_w  = (const float*)d_in[1];
    const float* pre_b  = (const float*)d_in[2];
    const float* post_w = (const float*)d_in[3];
    const float* post_b = (const float*)d_in[4];
    const float* w_ry   = (const float*)d_in[5];
    const float* w_rz   = (const float*)d_in[6];
    float* out = (float*)d_out;
    float2* trig = (float2*)d_ws;

    const int B = in_sizes[0] / 512;  // 4096

    dqc_trig_kernel<<<1, 128, 0, stream>>>(w_ry, w_rz, trig);
    dqc_main_kernel<<<(B + 3) / 4, 256, 0, stream>>>(x, pre_w, pre_b, post_w,
                                                     post_b, trig, out, B);
}

// Round 3
// 100.540 us; speedup vs baseline: 1.4124x; 1.2379x over previous
//
#include <hip/hip_runtime.h>

#define DEV static __device__ __forceinline__

// ---- lane-exchange primitives ----
template <int CTRL>
DEV float dpp_xor(float v) {
    int i = __float_as_int(v);
    i = __builtin_amdgcn_update_dpp(i, i, CTRL, 0xF, 0xF, false);
    return __int_as_float(i);
}
template <int PAT>
DEV float swz(float v) {
    return __int_as_float(__builtin_amdgcn_ds_swizzle(__float_as_int(v), PAT));
}
DEV float bperm(int byteaddr, float v) {
    return __int_as_float(__builtin_amdgcn_ds_bpermute(byteaddr, __float_as_int(v)));
}

// xor-exchange: masks 1,2,8 on VALU (DPP); 4,16 via ds_swizzle; 32 via bpermute(a32)
template <int MASK>
DEV float lanexor(float v, int a32) {
    if constexpr (MASK == 1)       return dpp_xor<0xB1>(v);   // quad_perm [1,0,3,2]
    else if constexpr (MASK == 2)  return dpp_xor<0x4E>(v);   // quad_perm [2,3,0,1]
    else if constexpr (MASK == 8)  return dpp_xor<0x128>(v);  // row_ror:8 == xor 8
    else if constexpr (MASK == 4)  return swz<0x101F>(v);     // BitMode xor=4
    else if constexpr (MASK == 16) return swz<0x401F>(v);     // BitMode xor=16
    else                           return bperm(a32, v);      // xor 32
}

DEV float wave_sum(float v, int a32) {
    v += lanexor<1>(v, 0);
    v += lanexor<2>(v, 0);
    v += lanexor<4>(v, 0);
    v += lanexor<8>(v, 0);
    v += lanexor<16>(v, 0);
    v += bperm(a32, v);
    return v;
}

// Qubit q <-> bit P = 9-q of state index s = lane*16 + r.
// Lane bits 5..0 = state bits 9..4; reg bits 3..0 = state bits 3..0.

template <int P>
DEV void apply_ry(float (&re)[16], float (&im)[16], float c, float s, int lane, int a32) {
    if constexpr (P >= 4) {
        constexpr int mask = 1 << (P - 4);
        const float sg = (lane & mask) ? s : -s;
#pragma unroll
        for (int r = 0; r < 16; ++r) {
            float pr = lanexor<mask>(re[r], a32);
            float pi = lanexor<mask>(im[r], a32);
            re[r] = fmaf(c, re[r], sg * pr);
            im[r] = fmaf(c, im[r], sg * pi);
        }
    } else {
        constexpr int tb = 1 << P;
#pragma unroll
        for (int r = 0; r < 16; ++r) {
            if (!(r & tb)) {
                const int r2 = r | tb;
                float a0r = re[r], a1r = re[r2];
                float a0i = im[r], a1i = im[r2];
                re[r]  = fmaf(c, a0r, -s * a1r);
                re[r2] = fmaf(s, a0r,  c * a1r);
                im[r]  = fmaf(c, a0i, -s * a1i);
                im[r2] = fmaf(s, a0i,  c * a1i);
            }
        }
    }
}

// Composed lane map of CNOT chain C(q0->q1)..C(q4->q5).
// g = f1(f2(f3(f4(f5(d))))): innermost is the LAST-applied gate C(q4->q5).
DEV int g_of(int a) {
    a ^= ((a >> 1) & 1) ? 1 : 0;   // C(q4->q5): ctrl lane bit1 -> tgt bit0
    a ^= ((a >> 2) & 1) ? 2 : 0;   // C(q3->q4)
    a ^= ((a >> 3) & 1) ? 4 : 0;   // C(q2->q3)
    a ^= ((a >> 4) & 1) ? 8 : 0;   // C(q1->q2)
    a ^= ((a >> 5) & 1) ? 16 : 0;  // C(q0->q1): ctrl lane bit5 -> tgt bit4
    return a;
}

// Precompute cos/sin of weight angles (batch-independent) into workspace.
__global__ void dqc_trig_kernel(const float* __restrict__ w_ry,
                                const float* __restrict__ w_rz,
                                float2* __restrict__ trig) {
    int t = threadIdx.x;  // 0..79
    if (t < 80) {
        float ang = (t < 40 ? w_ry[t] : w_rz[t - 40]) * 0.5f;
        trig[t] = make_float2(__cosf(ang), __sinf(ang));
    }
}

__global__ __launch_bounds__(256, 4) void dqc_main_kernel(
    const float* __restrict__ x, const float* __restrict__ pre_w,
    const float* __restrict__ pre_b, const float* __restrict__ post_w,
    const float* __restrict__ post_b, const float2* __restrict__ trig,
    float* __restrict__ out, int B) {
    const int lane = threadIdx.x & 63;
    const int wid = threadIdx.x >> 6;
    const int b = blockIdx.x * 4 + wid;
    if (b >= B) return;

    // precomputed exchange addresses (bytes)
    const int a32 = (lane ^ 32) << 2;
    // Composed CNOT addresses. C(q9->q0) conjugated back through the reg-CNOTs
    // becomes: flip lane bit5 iff (lane&1) ^ parity(r&15), applied between
    // C(q4->q5) and C(q5->q6). addr = g(h(d)).
    const int h0 = lane ^ ((lane & 1) ? 32 : 0);  // reg-parity 0 class
    const int cA = g_of(h0) << 2;
    const int cB = g_of(h0 ^ 32) << 2;

    // ---- q_in[b, i] = x[b] . pre_w[i] + pre_b[i] ----
    float th[10];
#pragma unroll
    for (int i = 0; i < 10; ++i) th[i] = 0.f;
    const float* xb = x + (size_t)b * 512;
#pragma unroll
    for (int k = 0; k < 8; ++k) {
        const int idx = lane + 64 * k;
        float xv = xb[idx];
#pragma unroll
        for (int i = 0; i < 10; ++i) th[i] = fmaf(xv, pre_w[i * 512 + idx], th[i]);
    }
#pragma unroll
    for (int i = 0; i < 10; ++i) th[i] = wave_sum(th[i], a32) + pre_b[i];

    // ---- product state after 10 initial RYs on |0..0>: purely real ----
    float cc[10], ss[10];
#pragma unroll
    for (int i = 0; i < 10; ++i) {
        float a = th[i] * 0.5f;
        cc[i] = __cosf(a);
        ss[i] = __sinf(a);
    }
    float laneP = 1.f;
#pragma unroll
    for (int i = 0; i < 6; ++i)  // qubit i <-> lane bit 5-i
        laneP *= ((lane >> (5 - i)) & 1) ? ss[i] : cc[i];
    float hi4[4], lo4[4];
#pragma unroll
    for (int j = 0; j < 4; ++j) {
        float f6 = (j >> 1) ? ss[6] : cc[6];
        float f7 = (j & 1) ? ss[7] : cc[7];
        hi4[j] = laneP * f6 * f7;
        float f8 = (j >> 1) ? ss[8] : cc[8];
        float f9 = (j & 1) ? ss[9] : cc[9];
        lo4[j] = f8 * f9;
    }
    float re[16], im[16];
#pragma unroll
    for (int r = 0; r < 16; ++r) { re[r] = hi4[r >> 2] * lo4[r & 3]; im[r] = 0.f; }

    // ---- variational layers ----
#pragma unroll 1
    for (int l = 0; l < 4; ++l) {
        const float2* tr = trig + l * 10;       // RY(layer, qubit)
        const float2* tz = trig + 40 + l * 10;  // RZ(layer, qubit)

        // All 10 RYs (RZs deferred: RZ(q) commutes with RY(q'!=q))
        apply_ry<9>(re, im, tr[0].x, tr[0].y, lane, a32);
        apply_ry<8>(re, im, tr[1].x, tr[1].y, lane, a32);
        apply_ry<7>(re, im, tr[2].x, tr[2].y, lane, a32);
        apply_ry<6>(re, im, tr[3].x, tr[3].y, lane, a32);
        apply_ry<5>(re, im, tr[4].x, tr[4].y, lane, a32);
        apply_ry<4>(re, im, tr[5].x, tr[5].y, lane, a32);
        apply_ry<3>(re, im, tr[6].x, tr[6].y, lane, a32);
        apply_ry<2>(re, im, tr[7].x, tr[7].y, lane, a32);
        apply_ry<1>(re, im, tr[8].x, tr[8].y, lane, a32);
        apply_ry<0>(re, im, tr[9].x, tr[9].y, lane, a32);

        // Combined diagonal phase for all 10 RZs.
        // qubit q bit value: q0..q5 -> lane bit (5-q); q6..q9 -> reg bit (9-q).
        // bit=0 amp scales by e^{-i phi/2} = (c, -s); bit=1 by (c, +s).
        float plr, pli;
        {
            float2 z0 = tz[0];
            pli = ((lane >> 5) & 1) ? z0.y : -z0.y;
            plr = z0.x;
#pragma unroll
            for (int q = 1; q < 6; ++q) {
                float2 z = tz[q];
                float sq = ((lane >> (5 - q)) & 1) ? z.y : -z.y;
                float nr = plr * z.x - pli * sq;
                float ni = plr * sq + pli * z.x;
                plr = nr; pli = ni;
            }
        }
        float p67r[4], p67i[4], p89r[4], p89i[4];
        {
            const float c6 = tz[6].x, s6 = tz[6].y, c7 = tz[7].x, s7 = tz[7].y;
            const float c8 = tz[8].x, s8 = tz[8].y, c9 = tz[9].x, s9 = tz[9].y;
#pragma unroll
            for (int j = 0; j < 4; ++j) {
                float sg6 = (j >> 1) ? s6 : -s6;  // qubit6 <-> reg bit 3
                float sg7 = (j & 1) ? s7 : -s7;   // qubit7 <-> reg bit 2
                float ar = c6 * c7 - sg6 * sg7;
                float ai = c6 * sg7 + sg6 * c7;
                p67r[j] = ar * plr - ai * pli;    // fold lane phase in
                p67i[j] = ar * pli + ai * plr;
                float sg8 = (j >> 1) ? s8 : -s8;  // qubit8 <-> reg bit 1
                float sg9 = (j & 1) ? s9 : -s9;   // qubit9 <-> reg bit 0
                p89r[j] = c8 * c9 - sg8 * sg9;
                p89i[j] = c8 * sg9 + sg8 * c9;
            }
        }
#pragma unroll
        for (int r = 0; r < 16; ++r) {
            const int j = r >> 2, k = r & 3;
            float t_r = re[r] * p67r[j] - im[r] * p67i[j];
            float t_i = re[r] * p67i[j] + im[r] * p67r[j];
            re[r] = t_r * p89r[k] - t_i * p89i[k];
            im[r] = t_r * p89i[k] + t_i * p89r[k];
        }

        // CNOT ring:
        // (1) composed lane permutation: C(q0->q1)..C(q4->q5) + conjugated C(q9->q0)
#pragma unroll
        for (int r = 0; r < 16; ++r) {
            const int addr = ((0x6996 >> r) & 1) ? cB : cA;  // parity of r&15
            re[r] = bperm(addr, re[r]);
            im[r] = bperm(addr, im[r]);
        }
        // (2) C(q5->q6): lane bit0 control, reg bit3 target
        {
            const bool ctrl = (lane & 1) != 0;
#pragma unroll
            for (int r = 0; r < 8; ++r) {
                const int r2 = r | 8;
                float t0 = re[r], t1 = re[r2];
                re[r]  = ctrl ? t1 : t0;
                re[r2] = ctrl ? t0 : t1;
                float u0 = im[r], u1 = im[r2];
                im[r]  = ctrl ? u1 : u0;
                im[r2] = ctrl ? u0 : u1;
            }
        }
        // (3) register renames: C(q6->q7), C(q7->q8), C(q8->q9)
#pragma unroll
        for (int r = 0; r < 16; ++r)
            if ((r & 8) && !(r & 4)) {
                const int r2 = r | 4;
                float t = re[r]; re[r] = re[r2]; re[r2] = t;
                t = im[r]; im[r] = im[r2]; im[r2] = t;
            }
#pragma unroll
        for (int r = 0; r < 16; ++r)
            if ((r & 4) && !(r & 2)) {
                const int r2 = r | 2;
                float t = re[r]; re[r] = re[r2]; re[r2] = t;
                t = im[r]; im[r] = im[r2]; im[r2] = t;
            }
#pragma unroll
        for (int r = 0; r < 16; ++r)
            if ((r & 2) && !(r & 1)) {
                const int r2 = r | 1;
                float t = re[r]; re[r] = re[r2]; re[r2] = t;
                t = im[r]; im[r] = im[r2]; im[r2] = t;
            }
    }

    // ---- out[b] = sum_s |psi_s|^2 * sum_j post_w[j]*(1-2*bit_j(s)) + post_b ----
    float laneC = 0.f;
#pragma unroll
    for (int j = 0; j < 6; ++j) {
        int bit = (lane >> (5 - j)) & 1;
        laneC += post_w[j] * (1.f - 2.f * (float)bit);
    }
    float acc = 0.f;
#pragma unroll
    for (int r = 0; r < 16; ++r) {
        float regC = 0.f;
#pragma unroll
        for (int j = 6; j < 10; ++j) {
            int bit = (r >> (9 - j)) & 1;
            regC += post_w[j] * (1.f - 2.f * (float)bit);
        }
        float p = fmaf(re[r], re[r], im[r] * im[r]);
        acc = fmaf(p, laneC + regC, acc);
    }
    acc = wave_sum(acc, a32);
    if (lane == 0) out[b] = acc + post_b[0];
}

extern "C" void kernel_launch(void* const* d_in, const int* in_sizes, int n_in,
                              void* d_out, int out_size, void* d_ws, size_t ws_size,
                              hipStream_t stream) {
    const float* x      = (const float*)d_in[0];
    const float* pre_w  = (const float*)d_in[1];
    const float* pre_b  = (const float*)d_in[2];
    const float* post_w = (const float*)d_in[3];
    const float* post_b = (const float*)d_in[4];
    const float* w_ry   = (const float*)d_in[5];
    const float* w_rz   = (const float*)d_in[6];
    float* out = (float*)d_out;
    float2* trig = (float2*)d_ws;

    const int B = in_sizes[0] / 512;  // 4096

    dqc_trig_kernel<<<1, 128, 0, stream>>>(w_ry, w_rz, trig);
    dqc_main_kernel<<<(B + 3) / 4, 256, 0, stream>>>(x, pre_w, pre_b, post_w,
                                                     post_b, trig, out, B);
}